// Round 4
// baseline (265.007 us; speedup 1.0000x reference)
//
#include <hip/hip_runtime.h>

typedef unsigned short u16;
typedef float  f32x4  __attribute__((ext_vector_type(4)));
typedef __bf16 bf16x8 __attribute__((ext_vector_type(8)));
typedef u16    u16x4  __attribute__((ext_vector_type(4)));

#define D_MODEL 1024
#define D_INNER 2048
#define B_SZ    2
#define SEQ     4096
#define MROWS   (B_SZ * SEQ)       // 8192
#define LTAPS   64                 // f[tau] ~ 0.4^tau -> negligible at 64
#define VROW    136                // VT row stride (u16): 272 B, 16B-aligned

__device__ __forceinline__ u16 f2bf(float f) {
    return __builtin_bit_cast(u16, (__bf16)f);   // HW v_cvt (RTNE) on gfx950
}
__device__ __forceinline__ float bf2f(u16 h) {
    unsigned u = ((unsigned)h) << 16;
    return __builtin_bit_cast(float, u);
}

typedef __attribute__((address_space(1))) void gv_t;
typedef __attribute__((address_space(3))) void lv_t;
__device__ __forceinline__ void glds16(const u16* g, u16* l) {
    __builtin_amdgcn_global_load_lds((gv_t*)g, (lv_t*)l, 16, 0, 0);
}
// s_waitcnt vmcnt(0) only (expcnt/lgkmcnt max) — no compiler memory clobber
__device__ __forceinline__ void wait_vm0() { __builtin_amdgcn_s_waitcnt(0x0F70); }

// ---------------------------------------------------------------------------
// Prep (one launch): blocks [0,8192) cvt x->bf16; [8192,10240) transpose Win;
// [10240,12288) transpose Wout; block 12288 builds Amat64[64][128] bf16:
// Amat64[i][j] = f[64+i-j], f[tau] = Cp^T tanh(A)^tau Bp (+Dp at tau=0).
// ---------------------------------------------------------------------------
__device__ __forceinline__ void transpose_tile(
    const float* __restrict__ in, u16* __restrict__ out,
    int R, int C, int c0, int r0, int tid, float (*tile)[33])
{
    const int tx = tid & 31, ty = tid >> 5;   // 32 x 8
    for (int k = 0; k < 32; k += 8)
        tile[ty + k][tx] = in[(size_t)(r0 + ty + k) * C + c0 + tx];
    __syncthreads();
    for (int k = 0; k < 32; k += 8)
        out[(size_t)(c0 + ty + k) * R + r0 + tx] = f2bf(tile[tx][ty + k]);
}

__global__ __launch_bounds__(256) void prep_kernel(
    const float* __restrict__ x, u16* __restrict__ xb,
    const float* __restrict__ Win, u16* __restrict__ WinT,
    const float* __restrict__ Wout, u16* __restrict__ WoutT,
    const float* __restrict__ A, const float* __restrict__ Bp,
    const float* __restrict__ Cp, const float* __restrict__ Dp,
    u16* __restrict__ Amat64)
{
    __shared__ float tile[32][33];
    __shared__ float fs[LTAPS];
    const int bx = blockIdx.x, tid = threadIdx.x;
    if (bx < 8192) {
        size_t i = ((size_t)bx * 256 + tid) * 4;
        f32x4 v = *(const f32x4*)(x + i);
        u16x4 o;
        o.x = f2bf(v.x); o.y = f2bf(v.y); o.z = f2bf(v.z); o.w = f2bf(v.w);
        *(u16x4*)(xb + i) = o;
    } else if (bx < 10240) {
        const int flat = bx - 8192;                      // Win: 1024 x 2048
        transpose_tile(Win, WinT, 1024, 2048,
                       (flat & 63) * 32, (flat >> 6) * 32, tid, tile);
    } else if (bx < 12288) {
        const int flat = bx - 10240;                     // Wout: 2048 x 1024
        transpose_tile(Wout, WoutT, 2048, 1024,
                       (flat & 31) * 32, (flat >> 5) * 32, tid, tile);
    } else {
        if (tid < 64) {
            const int i = tid & 15;          // lanes replicate in groups of 16
            float Atr[16];
            for (int j = 0; j < 16; j++) Atr[j] = tanhf(A[i * 16 + j]);
            float p = Bp[i];
            const float c  = Cp[i];
            const float d0 = Dp[0];
            for (int t = 0; t < LTAPS; t++) {
                float fv = c * p;
                fv += __shfl_xor(fv, 1); fv += __shfl_xor(fv, 2);
                fv += __shfl_xor(fv, 4); fv += __shfl_xor(fv, 8);
                if (tid == 0) fs[t] = fv + (t == 0 ? d0 : 0.f);
                float n0 = 0.f, n1 = 0.f, n2 = 0.f, n3 = 0.f;
                #pragma unroll
                for (int j = 0; j < 4; j++) {
                    n0 = fmaf(Atr[j],      __shfl(p, j),      n0);
                    n1 = fmaf(Atr[j + 4],  __shfl(p, j + 4),  n1);
                    n2 = fmaf(Atr[j + 8],  __shfl(p, j + 8),  n2);
                    n3 = fmaf(Atr[j + 12], __shfl(p, j + 12), n3);
                }
                p = (n0 + n1) + (n2 + n3);
            }
        }
        __syncthreads();
        for (int idx = tid; idx < 64 * 128; idx += 256) {
            const int i = idx >> 7, j = idx & 127;
            const int tau = 64 + i - j;
            float v = (tau >= 0 && tau < LTAPS) ? fs[tau] : 0.f;
            Amat64[idx] = f2bf(v);
        }
    }
}

// ---------------------------------------------------------------------------
// bt-GEMM, m97 structure: C[m][n] = sum_k A[m][k]*BT[n][k] + bias[n]
// BM=BN=128, BK=32, 256 thr (4 waves, 64x64 quadrant each), 16x16x32 bf16 MFMA
// MFMA operands SWAPPED (bfr, af): C/D col=lane&15 -> A-row (m), and each
// thread's f32x4 holds 4 CONSECUTIVE n-columns -> vectorized stores.
// XCD-aware tile remap. MODE 0: store bf16 (u16x4); MODE 1: store fp32 (f32x4)
// ---------------------------------------------------------------------------
template <int MODE>
__global__ __launch_bounds__(256) void gemm_bt_kernel(
    const u16* __restrict__ A, const u16* __restrict__ BT,
    void* __restrict__ Cout, const float* __restrict__ bias,
    int M, int N, int K)
{
    __shared__ u16 As[128 * 32];
    __shared__ u16 Bs[128 * 32];
    const int tid = threadIdx.x, lane = tid & 63, wid = tid >> 6;
    const int nTiles = gridDim.x;
    const int bid = blockIdx.x + nTiles * blockIdx.y;
    const int xcd = bid & 7;
    const int loc = bid >> 3;
    const int mt  = xcd * (gridDim.y >> 3) + (loc & 7);
    const int nt  = loc >> 3;
    const int m0 = mt * 128, n0 = nt * 128;
    const int sr = wid * 32 + (lane >> 2);
    const int sc = (lane & 3) * 8;
    const u16* ga = A  + (size_t)(m0 + sr) * K + sc;
    const u16* gb = BT + (size_t)(n0 + sr) * K + sc;
    u16* la = As + wid * 1024;
    u16* lb = Bs + wid * 1024;
    const int wm = (wid & 1) * 64, wn = (wid >> 1) * 64;
    const int fr = lane & 15, fq = lane >> 4;
    f32x4 acc[4][4] = {};
    for (int k0 = 0; k0 < K; k0 += 32) {
        glds16(ga + k0, la);
        glds16(ga + k0 + (size_t)16 * K, la + 512);
        glds16(gb + k0, lb);
        glds16(gb + k0 + (size_t)16 * K, lb + 512);
        wait_vm0();
        __syncthreads();
        bf16x8 af[4], bfr[4];
        for (int i = 0; i < 4; i++)
            af[i]  = *(const bf16x8*)(As + (wm + i * 16 + fr) * 32 + fq * 8);
        for (int i = 0; i < 4; i++)
            bfr[i] = *(const bf16x8*)(Bs + (wn + i * 16 + fr) * 32 + fq * 8);
        for (int mi = 0; mi < 4; mi++)
            for (int ni = 0; ni < 4; ni++)
                acc[mi][ni] = __builtin_amdgcn_mfma_f32_16x16x32_bf16(
                    bfr[ni], af[mi], acc[mi][ni], 0, 0, 0);
        __syncthreads();
    }
    // epilogue: thread owns row m = ..+fr, cols n = ..+fq*4+{0..3}
    for (int ni = 0; ni < 4; ni++) {
        const int colb = n0 + wn + ni * 16 + fq * 4;
        const f32x4 bv = *(const f32x4*)(bias + colb);
        for (int mi = 0; mi < 4; mi++) {
            const int row = m0 + wm + mi * 16 + fr;
            f32x4 v = acc[mi][ni];
            v.x += bv.x; v.y += bv.y; v.z += bv.z; v.w += bv.w;
            if constexpr (MODE == 0) {
                u16x4 o;
                o.x = f2bf(v.x); o.y = f2bf(v.y); o.z = f2bf(v.z); o.w = f2bf(v.w);
                *(u16x4*)((u16*)Cout + (size_t)row * N + colb) = o;
            } else {
                *(f32x4*)((float*)Cout + (size_t)row * N + colb) = v;
            }
        }
    }
}

// ---------------------------------------------------------------------------
// Fused depthwise-conv(4) + 64-tap FIR (MFMA Toeplitz) + silu.
// Block: 64 t x 128 c, one batch. Conv fills VT[c][s] (bf16, s-window
// [t0-64, t0+64), row stride VROW=136). FIR (operands swapped): each thread's
// f32x4 holds 4 consecutive channels at one t -> vectorized u16x4 Y stores.
// grid (16 c-tiles, 64 t-tiles, 2 batch) = 2048 blocks, 256 thr.
// ---------------------------------------------------------------------------
__global__ __launch_bounds__(256) void conv_fir_mfma_kernel(
    const u16* __restrict__ u, const float* __restrict__ cw,
    const float* __restrict__ cb, const u16* __restrict__ Amat64,
    u16* __restrict__ Y)
{
    __shared__ u16 VT[128 * VROW];          // 34816 B
    const int tid = threadIdx.x;
    const int c0 = blockIdx.x * 128, t0 = blockIdx.y * 64, b = blockIdx.z;
    // ---- conv phase: thread = one channel column, 64 consecutive s ----
    {
        const int tx = tid & 127, ty = tid >> 7;
        const int cg = c0 + tx;
        const float w0 = cw[cg * 4 + 0], w1 = cw[cg * 4 + 1];
        const float w2 = cw[cg * 4 + 2], w3 = cw[cg * 4 + 3];
        const float cbv = cb[cg];
        const u16* ucol = u + (size_t)b * SEQ * D_INNER + cg;
        const int s0 = t0 - 64 + ty * 64;
        u16* vrow = VT + tx * VROW + ty * 64;
        if (s0 + 63 < 0) {                       // whole half < 0 (t0==0, ty==0)
            const u16x4 z = {0, 0, 0, 0};
            #pragma unroll
            for (int j = 0; j < 16; j++) *(u16x4*)(vrow + j * 4) = z;
        } else {                                 // here s0 >= 0 always
            float xm3 = (s0 - 3 >= 0) ? bf2f(ucol[(size_t)(s0 - 3) * D_INNER]) : 0.f;
            float xm2 = (s0 - 2 >= 0) ? bf2f(ucol[(size_t)(s0 - 2) * D_INNER]) : 0.f;
            float xm1 = (s0 - 1 >= 0) ? bf2f(ucol[(size_t)(s0 - 1) * D_INNER]) : 0.f;
            #pragma unroll 4
            for (int j = 0; j < 16; j++) {
                const u16* p = ucol + (size_t)(s0 + j * 4) * D_INNER;
                float x0 = bf2f(p[0]);
                float x1 = bf2f(p[(size_t)D_INNER]);
                float x2 = bf2f(p[(size_t)2 * D_INNER]);
                float x3 = bf2f(p[(size_t)3 * D_INNER]);
                u16x4 o;
                o.x = f2bf(cbv + w0 * xm3 + w1 * xm2 + w2 * xm1 + w3 * x0);
                o.y = f2bf(cbv + w0 * xm2 + w1 * xm1 + w2 * x0  + w3 * x1);
                o.z = f2bf(cbv + w0 * xm1 + w1 * x0  + w2 * x1  + w3 * x2);
                o.w = f2bf(cbv + w0 * x0  + w1 * x1  + w2 * x2  + w3 * x3);
                *(u16x4*)(vrow + j * 4) = o;
                xm3 = x1; xm2 = x2; xm1 = x3;
            }
        }
    }
    __syncthreads();
    // ---- FIR phase: 4 waves, each 32t x 64c quadrant ----
    const int lane = tid & 63, wid = tid >> 6;
    const int wm = (wid & 1) * 32, wn = (wid >> 1) * 64;
    const int fr = lane & 15, fq = lane >> 4;
    f32x4 acc[2][4] = {};
    #pragma unroll
    for (int kq = 0; kq < 4; kq++) {
        const int k0 = kq * 32;
        bf16x8 af[2], bfr[4];
        #pragma unroll
        for (int mi = 0; mi < 2; mi++)
            af[mi] = *(const bf16x8*)(Amat64 + (wm + mi * 16 + fr) * 128 + k0 + fq * 8);
        #pragma unroll
        for (int ni = 0; ni < 4; ni++)
            bfr[ni] = *(const bf16x8*)(VT + (wn + ni * 16 + fr) * VROW + k0 + fq * 8);
        #pragma unroll
        for (int mi = 0; mi < 2; mi++)
            #pragma unroll
            for (int ni = 0; ni < 4; ni++)
                acc[mi][ni] = __builtin_amdgcn_mfma_f32_16x16x32_bf16(
                    bfr[ni], af[mi], acc[mi][ni], 0, 0, 0);
    }
    // epilogue: thread owns t = ..+fr, channels c = ..+fq*4+{0..3}
    #pragma unroll
    for (int ni = 0; ni < 4; ni++) {
        const int cbase = c0 + wn + ni * 16 + fq * 4;
        #pragma unroll
        for (int mi = 0; mi < 2; mi++) {
            const int trow = t0 + wm + mi * 16 + fr;
            f32x4 v = acc[mi][ni];
            u16x4 o;
            o.x = f2bf(v.x / (1.f + __expf(-v.x)));
            o.y = f2bf(v.y / (1.f + __expf(-v.y)));
            o.z = f2bf(v.z / (1.f + __expf(-v.z)));
            o.w = f2bf(v.w / (1.f + __expf(-v.w)));
            *(u16x4*)(Y + ((size_t)(b * SEQ + trow)) * D_INNER + cbase) = o;
        }
    }
}

// ---------------------------------------------------------------------------
extern "C" void kernel_launch(void* const* d_in, const int* in_sizes, int n_in,
                              void* d_out, int out_size, void* d_ws, size_t ws_size,
                              hipStream_t stream)
{
    const float* x    = (const float*)d_in[0];
    const float* Win  = (const float*)d_in[1];
    const float* bin  = (const float*)d_in[2];
    const float* cw   = (const float*)d_in[3];
    const float* cb   = (const float*)d_in[4];
    const float* A    = (const float*)d_in[5];
    const float* Bp   = (const float*)d_in[6];
    const float* Cp   = (const float*)d_in[7];
    const float* Dp   = (const float*)d_in[8];
    const float* Wout = (const float*)d_in[9];
    const float* bout = (const float*)d_in[10];
    float* out = (float*)d_out;

    char* ws = (char*)d_ws;
    u16* xb     = (u16*)(ws);                      // 8192x1024 bf16   16 MB
    u16* WinT   = (u16*)(ws + 16777216);           // 2048x1024 bf16    4 MB
    u16* WoutT  = (u16*)(ws + 20971520);           // 1024x2048 bf16    4 MB
    u16* u      = (u16*)(ws + 25165824);           // 8192x2048 bf16   32 MB
    u16* Y      = (u16*)(ws + 58720256);           // 8192x2048 bf16   32 MB
    u16* Amat64 = (u16*)(ws + 92274688);           // 64x128 bf16      16 KB

    // all conversions/transposes/setup in one launch
    prep_kernel<<<12289, 256, 0, stream>>>(x, xb, Win, WinT, Wout, WoutT,
                                           A, Bp, Cp, Dp, Amat64);
    // u = x @ W_in + b_in  (bf16 out)
    gemm_bt_kernel<0><<<dim3(16, 64), 256, 0, stream>>>(xb, WinT, u, bin,
                                                        MROWS, D_INNER, D_MODEL);
    // fused conv + SSM-as-FIR (MFMA Toeplitz) + silu -> Y
    conv_fir_mfma_kernel<<<dim3(16, 64, 2), 256, 0, stream>>>(u, cw, cb, Amat64, Y);
    // out = Y @ W_out + b_out  (fp32 out)
    gemm_bt_kernel<1><<<dim3(8, 64), 256, 0, stream>>>(Y, WoutT, out, bout,
                                                       MROWS, D_MODEL, D_INNER);
}

// Round 5
// 241.082 us; speedup vs baseline: 1.0992x; 1.0992x over previous
//
#include <hip/hip_runtime.h>

typedef unsigned short u16;
typedef float  f32x4  __attribute__((ext_vector_type(4)));
typedef __bf16 bf16x8 __attribute__((ext_vector_type(8)));
typedef u16    u16x2  __attribute__((ext_vector_type(2)));
typedef u16    u16x4  __attribute__((ext_vector_type(4)));

#define D_MODEL 1024
#define D_INNER 2048
#define B_SZ    2
#define SEQ     4096
#define MROWS   (B_SZ * SEQ)       // 8192
#define LTAPS   64                 // f[tau] ~ 0.4^tau -> negligible at 64
#define VROW    136                // VT row stride (u16): 272 B, 16B-aligned

__device__ __forceinline__ u16 f2bf(float f) {
    return __builtin_bit_cast(u16, (__bf16)f);   // HW v_cvt (RTNE) on gfx950
}
__device__ __forceinline__ float bf2f(u16 h) {
    unsigned u = ((unsigned)h) << 16;
    return __builtin_bit_cast(float, u);
}

typedef __attribute__((address_space(1))) void gv_t;
typedef __attribute__((address_space(3))) void lv_t;
__device__ __forceinline__ void glds16(const u16* g, u16* l) {
    __builtin_amdgcn_global_load_lds((gv_t*)g, (lv_t*)l, 16, 0, 0);
}
// gfx9 waitcnt imm: vm[3:0]+[15:14], exp[6:4], lgkm[11:8]
#define WAIT_VM0   0x0F70   // vmcnt(0), others max
#define WAIT_LGKM0 0xC07F   // lgkmcnt(0), others max

// ---------------------------------------------------------------------------
// Prep (one launch): blocks [0,8192) cvt x->bf16; [8192,10240) transpose Win;
// [10240,12288) transpose Wout; block 12288 builds Amat64[64][128] bf16:
// Amat64[i][j] = f[64+i-j], f[tau] = Cp^T tanh(A)^tau Bp (+Dp at tau=0).
// ---------------------------------------------------------------------------
__device__ __forceinline__ void transpose_tile(
    const float* __restrict__ in, u16* __restrict__ out,
    int R, int C, int c0, int r0, int tid, float (*tile)[33])
{
    const int tx = tid & 31, ty = tid >> 5;   // 32 x 8
    for (int k = 0; k < 32; k += 8)
        tile[ty + k][tx] = in[(size_t)(r0 + ty + k) * C + c0 + tx];
    __syncthreads();
    for (int k = 0; k < 32; k += 8)
        out[(size_t)(c0 + ty + k) * R + r0 + tx] = f2bf(tile[tx][ty + k]);
}

__global__ __launch_bounds__(256) void prep_kernel(
    const float* __restrict__ x, u16* __restrict__ xb,
    const float* __restrict__ Win, u16* __restrict__ WinT,
    const float* __restrict__ Wout, u16* __restrict__ WoutT,
    const float* __restrict__ A, const float* __restrict__ Bp,
    const float* __restrict__ Cp, const float* __restrict__ Dp,
    u16* __restrict__ Amat64)
{
    __shared__ float tile[32][33];
    __shared__ float fs[LTAPS];
    const int bx = blockIdx.x, tid = threadIdx.x;
    if (bx < 8192) {
        size_t i = ((size_t)bx * 256 + tid) * 4;
        f32x4 v = *(const f32x4*)(x + i);
        u16x4 o;
        o.x = f2bf(v.x); o.y = f2bf(v.y); o.z = f2bf(v.z); o.w = f2bf(v.w);
        *(u16x4*)(xb + i) = o;
    } else if (bx < 10240) {
        const int flat = bx - 8192;                      // Win: 1024 x 2048
        transpose_tile(Win, WinT, 1024, 2048,
                       (flat & 63) * 32, (flat >> 6) * 32, tid, tile);
    } else if (bx < 12288) {
        const int flat = bx - 10240;                     // Wout: 2048 x 1024
        transpose_tile(Wout, WoutT, 2048, 1024,
                       (flat & 31) * 32, (flat >> 5) * 32, tid, tile);
    } else {
        if (tid < 64) {
            const int i = tid & 15;          // lanes replicate in groups of 16
            float Atr[16];
            for (int j = 0; j < 16; j++) Atr[j] = tanhf(A[i * 16 + j]);
            float p = Bp[i];
            const float c  = Cp[i];
            const float d0 = Dp[0];
            for (int t = 0; t < LTAPS; t++) {
                float fv = c * p;
                fv += __shfl_xor(fv, 1); fv += __shfl_xor(fv, 2);
                fv += __shfl_xor(fv, 4); fv += __shfl_xor(fv, 8);
                if (tid == 0) fs[t] = fv + (t == 0 ? d0 : 0.f);
                float n0 = 0.f, n1 = 0.f, n2 = 0.f, n3 = 0.f;
                #pragma unroll
                for (int j = 0; j < 4; j++) {
                    n0 = fmaf(Atr[j],      __shfl(p, j),      n0);
                    n1 = fmaf(Atr[j + 4],  __shfl(p, j + 4),  n1);
                    n2 = fmaf(Atr[j + 8],  __shfl(p, j + 8),  n2);
                    n3 = fmaf(Atr[j + 12], __shfl(p, j + 12), n3);
                }
                p = (n0 + n1) + (n2 + n3);
            }
        }
        __syncthreads();
        for (int idx = tid; idx < 64 * 128; idx += 256) {
            const int i = idx >> 7, j = idx & 127;
            const int tau = 64 + i - j;
            float v = (tau >= 0 && tau < LTAPS) ? fs[tau] : 0.f;
            Amat64[idx] = f2bf(v);
        }
    }
}

// ---------------------------------------------------------------------------
// bt-GEMM: C[m][n] = sum_k A[m][k]*BT[n][k] + bias[n]
// BM=BN=128, BK=32, 256 thr, 16x16x32 bf16 MFMA (operands swapped: thread's
// f32x4 = 4 consecutive n-cols -> vectorized stores).
// K-loop: single LDS buffer + register-fragment prefetch. Per iter:
//   wait vm0; barrier (tile landed); ds_read all frags; wait lgkm0;
//   barrier (LDS free); issue NEXT tile's glds16; mfma.
// The glds latency overlaps the MFMA block instead of being drained at a
// __syncthreads. Raw s_barrier avoids the compiler's full vm/lgkm drain.
// XCD-aware tile remap. MODE 0: store bf16; MODE 1: store fp32.
// ---------------------------------------------------------------------------
template <int MODE>
__global__ __launch_bounds__(256) void gemm_bt_kernel(
    const u16* __restrict__ A, const u16* __restrict__ BT,
    void* __restrict__ Cout, const float* __restrict__ bias,
    int M, int N, int K)
{
    __shared__ u16 As[128 * 32];
    __shared__ u16 Bs[128 * 32];
    const int tid = threadIdx.x, lane = tid & 63, wid = tid >> 6;
    const int nTiles = gridDim.x;
    const int bid = blockIdx.x + nTiles * blockIdx.y;
    const int xcd = bid & 7;
    const int loc = bid >> 3;
    const int mt  = xcd * (gridDim.y >> 3) + (loc & 7);
    const int nt  = loc >> 3;
    const int m0 = mt * 128, n0 = nt * 128;
    const int sr = wid * 32 + (lane >> 2);
    const int sc = (lane & 3) * 8;
    const u16* ga = A  + (size_t)(m0 + sr) * K + sc;
    const u16* gb = BT + (size_t)(n0 + sr) * K + sc;
    u16* la = As + wid * 1024;
    u16* lb = Bs + wid * 1024;
    const int wm = (wid & 1) * 64, wn = (wid >> 1) * 64;
    const int fr = lane & 15, fq = lane >> 4;
    f32x4 acc[4][4] = {};
    // prologue: stage tile 0
    glds16(ga, la);
    glds16(ga + (size_t)16 * K, la + 512);
    glds16(gb, lb);
    glds16(gb + (size_t)16 * K, lb + 512);
    const int iters = K >> 5;
    for (int it = 0; it < iters; ++it) {
        __builtin_amdgcn_s_waitcnt(WAIT_VM0);     // staged tile landed in LDS
        __builtin_amdgcn_s_barrier();
        bf16x8 af[4], bfr[4];
        #pragma unroll
        for (int i = 0; i < 4; i++)
            af[i]  = *(const bf16x8*)(As + (wm + i * 16 + fr) * 32 + fq * 8);
        #pragma unroll
        for (int i = 0; i < 4; i++)
            bfr[i] = *(const bf16x8*)(Bs + (wn + i * 16 + fr) * 32 + fq * 8);
        asm volatile("" ::: "memory");            // pin ds_reads above the wait
        __builtin_amdgcn_s_waitcnt(WAIT_LGKM0);   // fragments in registers
        __builtin_amdgcn_s_barrier();             // LDS free for overwrite
        if (it + 1 < iters) {                     // stage next tile now;
            const int k0 = (it + 1) << 5;         // latency hides under MFMAs
            glds16(ga + k0, la);
            glds16(ga + k0 + (size_t)16 * K, la + 512);
            glds16(gb + k0, lb);
            glds16(gb + k0 + (size_t)16 * K, lb + 512);
        }
        #pragma unroll
        for (int mi = 0; mi < 4; mi++)
            #pragma unroll
            for (int ni = 0; ni < 4; ni++)
                acc[mi][ni] = __builtin_amdgcn_mfma_f32_16x16x32_bf16(
                    bfr[ni], af[mi], acc[mi][ni], 0, 0, 0);
    }
    // epilogue: thread owns row m = ..+fr, cols n = ..+fq*4+{0..3}
    for (int ni = 0; ni < 4; ni++) {
        const int colb = n0 + wn + ni * 16 + fq * 4;
        const f32x4 bv = *(const f32x4*)(bias + colb);
        for (int mi = 0; mi < 4; mi++) {
            const int row = m0 + wm + mi * 16 + fr;
            f32x4 v = acc[mi][ni];
            v.x += bv.x; v.y += bv.y; v.z += bv.z; v.w += bv.w;
            if constexpr (MODE == 0) {
                u16x4 o;
                o.x = f2bf(v.x); o.y = f2bf(v.y); o.z = f2bf(v.z); o.w = f2bf(v.w);
                *(u16x4*)((u16*)Cout + (size_t)row * N + colb) = o;
            } else {
                *(f32x4*)((float*)Cout + (size_t)row * N + colb) = v;
            }
        }
    }
}

// ---------------------------------------------------------------------------
// Fused depthwise-conv(4) + 64-tap FIR (MFMA Toeplitz) + silu.
// Block: 64 t x 128 c, one batch. Conv fills VT[c][s] (bf16, s-window
// [t0-64, t0+64), row stride VROW=136). Conv loads vectorized u16x2
// (2 channels/thread, 256 B/wave-instr). FIR operands swapped -> each
// thread's f32x4 = 4 consecutive channels -> vectorized u16x4 Y stores.
// grid (16 c-tiles, 64 t-tiles, 2 batch) = 2048 blocks, 256 thr.
// ---------------------------------------------------------------------------
__global__ __launch_bounds__(256) void conv_fir_mfma_kernel(
    const u16* __restrict__ u, const float* __restrict__ cw,
    const float* __restrict__ cb, const u16* __restrict__ Amat64,
    u16* __restrict__ Y)
{
    __shared__ u16 VT[128 * VROW];          // 34816 B
    const int tid = threadIdx.x;
    const int c0 = blockIdx.x * 128, t0 = blockIdx.y * 64, b = blockIdx.z;
    // ---- conv phase: thread = 2 channel columns, 32 consecutive s ----
    {
        const int tx = tid & 63, ty = tid >> 6;
        const int cg = c0 + tx * 2;
        const f32x4 wA = *(const f32x4*)(cw + cg * 4);       // ch cg
        const f32x4 wB = *(const f32x4*)(cw + cg * 4 + 4);   // ch cg+1
        const float cb0 = cb[cg], cb1 = cb[cg + 1];
        const u16* ucol = u + (size_t)b * SEQ * D_INNER + cg;
        const int s0 = t0 - 64 + ty * 32;
        u16* vr0 = VT + (tx * 2)     * VROW + ty * 32;
        u16* vr1 = VT + (tx * 2 + 1) * VROW + ty * 32;
        if (t0 == 0 && ty < 2) {                 // s in [-64,-1): all zero
            const u16x4 z = {0, 0, 0, 0};
            #pragma unroll
            for (int j = 0; j < 8; j++) {
                *(u16x4*)(vr0 + j * 4) = z;
                *(u16x4*)(vr1 + j * 4) = z;
            }
        } else {                                  // here s0 >= 0 always
            float am3 = 0.f, am2 = 0.f, am1 = 0.f;
            float bm3 = 0.f, bm2 = 0.f, bm1 = 0.f;
            if (s0 > 0) {
                u16x2 d3 = *(const u16x2*)(ucol + (size_t)(s0 - 3) * D_INNER);
                u16x2 d2 = *(const u16x2*)(ucol + (size_t)(s0 - 2) * D_INNER);
                u16x2 d1 = *(const u16x2*)(ucol + (size_t)(s0 - 1) * D_INNER);
                am3 = bf2f(d3.x); bm3 = bf2f(d3.y);
                am2 = bf2f(d2.x); bm2 = bf2f(d2.y);
                am1 = bf2f(d1.x); bm1 = bf2f(d1.y);
            }
            #pragma unroll 2
            for (int j = 0; j < 8; j++) {
                const u16* p = ucol + (size_t)(s0 + j * 4) * D_INNER;
                u16x2 r0 = *(const u16x2*)(p);
                u16x2 r1 = *(const u16x2*)(p + (size_t)D_INNER);
                u16x2 r2 = *(const u16x2*)(p + (size_t)2 * D_INNER);
                u16x2 r3 = *(const u16x2*)(p + (size_t)3 * D_INNER);
                float a0 = bf2f(r0.x), b0 = bf2f(r0.y);
                float a1 = bf2f(r1.x), b1 = bf2f(r1.y);
                float a2 = bf2f(r2.x), b2 = bf2f(r2.y);
                float a3 = bf2f(r3.x), b3 = bf2f(r3.y);
                u16x4 oa, ob;
                oa.x = f2bf(cb0 + wA.x * am3 + wA.y * am2 + wA.z * am1 + wA.w * a0);
                oa.y = f2bf(cb0 + wA.x * am2 + wA.y * am1 + wA.z * a0  + wA.w * a1);
                oa.z = f2bf(cb0 + wA.x * am1 + wA.y * a0  + wA.z * a1  + wA.w * a2);
                oa.w = f2bf(cb0 + wA.x * a0  + wA.y * a1  + wA.z * a2  + wA.w * a3);
                ob.x = f2bf(cb1 + wB.x * bm3 + wB.y * bm2 + wB.z * bm1 + wB.w * b0);
                ob.y = f2bf(cb1 + wB.x * bm2 + wB.y * bm1 + wB.z * b0  + wB.w * b1);
                ob.z = f2bf(cb1 + wB.x * bm1 + wB.y * b0  + wB.z * b1  + wB.w * b2);
                ob.w = f2bf(cb1 + wB.x * b0  + wB.y * b1  + wB.z * b2  + wB.w * b3);
                *(u16x4*)(vr0 + j * 4) = oa;
                *(u16x4*)(vr1 + j * 4) = ob;
                am3 = a1; am2 = a2; am1 = a3;
                bm3 = b1; bm2 = b2; bm1 = b3;
            }
        }
    }
    __syncthreads();
    // ---- FIR phase: 4 waves, each 32t x 64c quadrant ----
    const int lane = tid & 63, wid = tid >> 6;
    const int wm = (wid & 1) * 32, wn = (wid >> 1) * 64;
    const int fr = lane & 15, fq = lane >> 4;
    f32x4 acc[2][4] = {};
    #pragma unroll
    for (int kq = 0; kq < 4; kq++) {
        const int k0 = kq * 32;
        bf16x8 af[2], bfr[4];
        #pragma unroll
        for (int mi = 0; mi < 2; mi++)
            af[mi] = *(const bf16x8*)(Amat64 + (wm + mi * 16 + fr) * 128 + k0 + fq * 8);
        #pragma unroll
        for (int ni = 0; ni < 4; ni++)
            bfr[ni] = *(const bf16x8*)(VT + (wn + ni * 16 + fr) * VROW + k0 + fq * 8);
        #pragma unroll
        for (int mi = 0; mi < 2; mi++)
            #pragma unroll
            for (int ni = 0; ni < 4; ni++)
                acc[mi][ni] = __builtin_amdgcn_mfma_f32_16x16x32_bf16(
                    bfr[ni], af[mi], acc[mi][ni], 0, 0, 0);
    }
    // epilogue: thread owns t = ..+fr, channels c = ..+fq*4+{0..3}
    #pragma unroll
    for (int ni = 0; ni < 4; ni++) {
        const int cbase = c0 + wn + ni * 16 + fq * 4;
        #pragma unroll
        for (int mi = 0; mi < 2; mi++) {
            const int trow = t0 + wm + mi * 16 + fr;
            f32x4 v = acc[mi][ni];
            u16x4 o;
            o.x = f2bf(v.x / (1.f + __expf(-v.x)));
            o.y = f2bf(v.y / (1.f + __expf(-v.y)));
            o.z = f2bf(v.z / (1.f + __expf(-v.z)));
            o.w = f2bf(v.w / (1.f + __expf(-v.w)));
            *(u16x4*)(Y + ((size_t)(b * SEQ + trow)) * D_INNER + cbase) = o;
        }
    }
}

// ---------------------------------------------------------------------------
extern "C" void kernel_launch(void* const* d_in, const int* in_sizes, int n_in,
                              void* d_out, int out_size, void* d_ws, size_t ws_size,
                              hipStream_t stream)
{
    const float* x    = (const float*)d_in[0];
    const float* Win  = (const float*)d_in[1];
    const float* bin  = (const float*)d_in[2];
    const float* cw   = (const float*)d_in[3];
    const float* cb   = (const float*)d_in[4];
    const float* A    = (const float*)d_in[5];
    const float* Bp   = (const float*)d_in[6];
    const float* Cp   = (const float*)d_in[7];
    const float* Dp   = (const float*)d_in[8];
    const float* Wout = (const float*)d_in[9];
    const float* bout = (const float*)d_in[10];
    float* out = (float*)d_out;

    char* ws = (char*)d_ws;
    u16* xb     = (u16*)(ws);                      // 8192x1024 bf16   16 MB
    u16* WinT   = (u16*)(ws + 16777216);           // 2048x1024 bf16    4 MB
    u16* WoutT  = (u16*)(ws + 20971520);           // 1024x2048 bf16    4 MB
    u16* u      = (u16*)(ws + 25165824);           // 8192x2048 bf16   32 MB
    u16* Y      = (u16*)(ws + 58720256);           // 8192x2048 bf16   32 MB
    u16* Amat64 = (u16*)(ws + 92274688);           // 64x128 bf16      16 KB

    // all conversions/transposes/setup in one launch
    prep_kernel<<<12289, 256, 0, stream>>>(x, xb, Win, WinT, Wout, WoutT,
                                           A, Bp, Cp, Dp, Amat64);
    // u = x @ W_in + b_in  (bf16 out)
    gemm_bt_kernel<0><<<dim3(16, 64), 256, 0, stream>>>(xb, WinT, u, bin,
                                                        MROWS, D_INNER, D_MODEL);
    // fused conv + SSM-as-FIR (MFMA Toeplitz) + silu -> Y
    conv_fir_mfma_kernel<<<dim3(16, 64, 2), 256, 0, stream>>>(u, cw, cb, Amat64, Y);
    // out = Y @ W_out + b_out  (fp32 out)
    gemm_bt_kernel<1><<<dim3(8, 64), 256, 0, stream>>>(Y, WoutT, out, bout,
                                                       MROWS, D_MODEL, D_INNER);
}